// Round 1
// baseline (1152.522 us; speedup 1.0000x reference)
//
#include <hip/hip_runtime.h>

typedef float  floatx4 __attribute__((ext_vector_type(4)));
typedef short  short8  __attribute__((ext_vector_type(8)));
typedef unsigned short u16;
typedef unsigned int   u32;

#define WS_IMG_USHORTS (5 * 16384)   // 5 matrices, 128x128 bf16 each = 160 KB
#define WS_BIAS_OFF    163840        // byte offset of bias block in d_ws

// RTNE float->bf16, packed pair (a=low16, b=high16)
__device__ __forceinline__ u32 pk2(float a, float b) {
    u32 ua = __float_as_uint(a); ua += 0x7fffu + ((ua >> 16) & 1u);
    u32 ub = __float_as_uint(b); ub += 0x7fffu + ((ub >> 16) & 1u);
    return (ua >> 16) | (ub & 0xffff0000u);
}

union F8 { short8 v; u32 u[4]; };

__device__ __forceinline__ float sig(float v) {
    return __builtin_amdgcn_rcpf(1.f + __expf(-v));
}

// ---------------------------------------------------------------------------
// Prologue: build bf16 LDS image of weights in d_ws + bias column-sums.
// Image layout per matrix: row r holds k=0..127, in 16B chunks swizzled by
// chunk' = chunk ^ (r & 15).  Matrices: 0=Wz^T 1=Uz^T 2=(Wr+Ur)^T 3=W_h 4=U_h
// ---------------------------------------------------------------------------
__global__ void gru_prep(const float* __restrict__ Wz, const float* __restrict__ Uz,
                         const float* __restrict__ Bz, const float* __restrict__ Wr,
                         const float* __restrict__ Ur, const float* __restrict__ Br,
                         const float* __restrict__ Wh, const float* __restrict__ Uh,
                         const float* __restrict__ Bh, u16* __restrict__ img,
                         float* __restrict__ bias)
{
    int id = blockIdx.x * 256 + threadIdx.x;
    if (id < 10240) {                    // 5 mats * 128 rows * 16 chunks
        int mt = id >> 11;               // matrix
        int r  = (id >> 4) & 127;        // image row (output feature f)
        int c  = id & 15;                // 16B chunk (8 cols)
        int k0 = c << 3;
        float v[8];
#pragma unroll
        for (int j = 0; j < 8; ++j) {
            int k = k0 + j;
            float t;
            if      (mt == 0) t = Wz[k * 128 + r];            // Wz^T[f][k]
            else if (mt == 1) t = Uz[k * 128 + r];            // Uz^T[f][k]
            else if (mt == 2) t = Wr[k * 128 + r] + Ur[k * 128 + r];
            else if (mt == 3) t = Wh[r * 128 + k];            // W_h[f][k]
            else              t = Uh[r * 128 + k];            // U_h[f][k]
            v[j] = t;
        }
        F8 o;
        o.u[0] = pk2(v[0], v[1]); o.u[1] = pk2(v[2], v[3]);
        o.u[2] = pk2(v[4], v[5]); o.u[3] = pk2(v[6], v[7]);
        u16* dst = img + mt * 16384 + r * 128 + ((c ^ (r & 15)) << 3);
        *(short8*)dst = o.v;
    } else if (id < 10624) {             // 3 bias vectors (column sums)
        int tt = id - 10240;
        int which = tt >> 7;
        int f = tt & 127;
        const float* M = (which == 0) ? Bz : (which == 1) ? Br : Bh;
        float s = 0.f;
        for (int k = 0; k < 128; ++k) s += M[k * 128 + f];
        bias[tt] = s;                    // [0:128)=b_z [128:256)=b_r [256:384)=b_h
    }
}

// ---------------------------------------------------------------------------
// Main fused kernel: transposed-orientation MFMA GRU cell.
// Per wave: one 16-row batch tile; D-tiles are [16 feature x 16 batch].
// ---------------------------------------------------------------------------
__global__ __launch_bounds__(512) void gru_main(
    const float* __restrict__ x, const float* __restrict__ h,
    const u16* __restrict__ img, const float* __restrict__ bias,
    float* __restrict__ out, int Brows)
{
    __shared__ u16 wl[WS_IMG_USHORTS];   // 160 KB: all 5 weight matrices
    for (int i = threadIdx.x; i < WS_IMG_USHORTS / 8; i += 512)
        ((uint4*)wl)[i] = ((const uint4*)img)[i];
    __syncthreads();

    const int tid  = threadIdx.x;
    const int lane = tid & 63;
    const int wv   = tid >> 6;
    const int q    = lane >> 4;          // quad
    const int m    = lane & 15;          // A-operand row / batch lane / D col
    const int half = (lane >> 5) & 1;
    const int srcbase = ((lane & 16) << 1) | m;   // (q&1)<<5 | b
    const int ntiles = Brows >> 4;
    const int gw = blockIdx.x * 8 + wv;

    // A-fragment from LDS (ds_read_b128, XOR-swizzled)
    auto afrag = [&](int mat, int ft, int ks) -> short8 {
        return *(const short8*)(wl + mat * 16384 + (ft * 16 + m) * 128 +
                                ((((ks << 2) | q) ^ m) << 3));
    };

    for (int t = gw; t < ntiles; t += 2048) {
        const int b0 = t << 4;
        const float* xr = x + (size_t)(b0 + m) * 128;
        const float* hr = h + (size_t)(b0 + m) * 128;

        // ---- global loads (front-loaded) ----
        floatx4 xlo[4], xhi[4], hlo[4], hhi[4], hcd[8];
#pragma unroll
        for (int ks = 0; ks < 4; ++ks) {
            xlo[ks] = *(const floatx4*)(xr + ks * 32 + q * 8);
            xhi[ks] = *(const floatx4*)(xr + ks * 32 + q * 8 + 4);
            hlo[ks] = *(const floatx4*)(hr + ks * 32 + q * 8);
            hhi[ks] = *(const floatx4*)(hr + ks * 32 + q * 8 + 4);
        }
#pragma unroll
        for (int ft = 0; ft < 8; ++ft)      // h in C/D layout for rh + blend
            hcd[ft] = *(const floatx4*)(hr + ft * 16 + q * 4);

        // ---- convert to bf16 B-fragments (x^T, h^T) ----
        F8 xf[4], hf[4];
#pragma unroll
        for (int ks = 0; ks < 4; ++ks) {
            xf[ks].u[0] = pk2(xlo[ks][0], xlo[ks][1]);
            xf[ks].u[1] = pk2(xlo[ks][2], xlo[ks][3]);
            xf[ks].u[2] = pk2(xhi[ks][0], xhi[ks][1]);
            xf[ks].u[3] = pk2(xhi[ks][2], xhi[ks][3]);
            hf[ks].u[0] = pk2(hlo[ks][0], hlo[ks][1]);
            hf[ks].u[1] = pk2(hlo[ks][2], hlo[ks][3]);
            hf[ks].u[2] = pk2(hhi[ks][0], hhi[ks][1]);
            hf[ks].u[3] = pk2(hhi[ks][2], hhi[ks][3]);
        }

        // ---- reset gate: r^T = sigm((Wr+Ur)^T @ x^T + b_r) ----
        floatx4 accr[8];
#pragma unroll
        for (int ft = 0; ft < 8; ++ft) {
            floatx4 bv = *(const floatx4*)(bias + 128 + ft * 16 + q * 4);
            accr[ft] = bv;
        }
#pragma unroll
        for (int ks = 0; ks < 4; ++ks)
#pragma unroll
            for (int ft = 0; ft < 8; ++ft)
                accr[ft] = __builtin_amdgcn_mfma_f32_16x16x32_bf16(
                    afrag(2, ft, ks), xf[ks].v, accr[ft], 0, 0, 0);

        // ---- rh = sigm(r) * h, packed bf16 pairs in C/D layout ----
        u32 rhp[8][2];
#pragma unroll
        for (int ft = 0; ft < 8; ++ft) {
            float r0 = sig(accr[ft][0]) * hcd[ft][0];
            float r1 = sig(accr[ft][1]) * hcd[ft][1];
            float r2 = sig(accr[ft][2]) * hcd[ft][2];
            float r3 = sig(accr[ft][3]) * hcd[ft][3];
            rhp[ft][0] = pk2(r0, r1);
            rhp[ft][1] = pk2(r2, r3);
        }

        // ---- update gate: z^T = sigm(Wz^T @ x^T + Uz^T @ h^T + b_z) ----
        floatx4 accz[8];
#pragma unroll
        for (int ft = 0; ft < 8; ++ft) {
            floatx4 bv = *(const floatx4*)(bias + ft * 16 + q * 4);
            accz[ft] = bv;
        }
#pragma unroll
        for (int ks = 0; ks < 4; ++ks)
#pragma unroll
            for (int ft = 0; ft < 8; ++ft)
                accz[ft] = __builtin_amdgcn_mfma_f32_16x16x32_bf16(
                    afrag(0, ft, ks), xf[ks].v, accz[ft], 0, 0, 0);
#pragma unroll
        for (int ks = 0; ks < 4; ++ks)
#pragma unroll
            for (int ft = 0; ft < 8; ++ft)
                accz[ft] = __builtin_amdgcn_mfma_f32_16x16x32_bf16(
                    afrag(1, ft, ks), hf[ks].v, accz[ft], 0, 0, 0);

        // ---- candidate: hc^T = tanh(W_h @ x^T + U_h @ rh^T + b_h) ----
        floatx4 acch[8];
#pragma unroll
        for (int ft = 0; ft < 8; ++ft) {
            floatx4 bv = *(const floatx4*)(bias + 256 + ft * 16 + q * 4);
            acch[ft] = bv;
        }
#pragma unroll
        for (int ks = 0; ks < 4; ++ks)
#pragma unroll
            for (int ft = 0; ft < 8; ++ft)
                acch[ft] = __builtin_amdgcn_mfma_f32_16x16x32_bf16(
                    afrag(3, ft, ks), xf[ks].v, acch[ft], 0, 0, 0);

        // rh: C/D layout -> B-operand layout via in-register shuffles
#pragma unroll
        for (int ks = 0; ks < 4; ++ks) {
            F8 rb;
#pragma unroll
            for (int jp = 0; jp < 4; ++jp) {
                int src = srcbase + ((jp >> 1) << 4);
                int g0 = __shfl((int)rhp[2 * ks][jp & 1], src, 64);
                int g1 = __shfl((int)rhp[2 * ks + 1][jp & 1], src, 64);
                rb.u[jp] = half ? (u32)g1 : (u32)g0;
            }
#pragma unroll
            for (int ft = 0; ft < 8; ++ft)
                acch[ft] = __builtin_amdgcn_mfma_f32_16x16x32_bf16(
                    afrag(4, ft, ks), rb.v, acch[ft], 0, 0, 0);
        }

        // ---- epilogue: z, hc, blend, coalesced float4 stores ----
        float* o1 = out + (size_t)(b0 + m) * 128;
        float* o2 = out + (size_t)Brows * 128 + (size_t)(b0 + m) * 128;
#pragma unroll
        for (int ft = 0; ft < 8; ++ft) {
            floatx4 ht, hcv;
#pragma unroll
            for (int rg = 0; rg < 4; ++rg) {
                float z  = sig(accz[ft][rg]);
                float v  = acch[ft][rg];
                v = fminf(30.f, fmaxf(-30.f, v));
                float e  = __expf(-2.f * v);
                float hc = (1.f - e) * __builtin_amdgcn_rcpf(1.f + e);
                float hv = hcd[ft][rg];
                hcv[rg] = hc;
                ht[rg]  = hv + z * (hc - hv);
            }
            *(floatx4*)(o1 + ft * 16 + q * 4) = ht;
            *(floatx4*)(o2 + ft * 16 + q * 4) = hcv;
        }
    }
}

// ---------------------------------------------------------------------------
extern "C" void kernel_launch(void* const* d_in, const int* in_sizes, int n_in,
                              void* d_out, int out_size, void* d_ws, size_t ws_size,
                              hipStream_t stream)
{
    const float* x  = (const float*)d_in[0];
    const float* h  = (const float*)d_in[1];
    const float* Wz = (const float*)d_in[2];
    const float* Uz = (const float*)d_in[3];
    const float* Bz = (const float*)d_in[4];
    const float* Wr = (const float*)d_in[5];
    const float* Ur = (const float*)d_in[6];
    const float* Br = (const float*)d_in[7];
    const float* Wh = (const float*)d_in[8];
    const float* Uh = (const float*)d_in[9];
    const float* Bh = (const float*)d_in[10];
    int Brows = in_sizes[0] / 128;

    u16*   img  = (u16*)d_ws;
    float* bias = (float*)((char*)d_ws + WS_BIAS_OFF);

    gru_prep<<<42, 256, 0, stream>>>(Wz, Uz, Bz, Wr, Ur, Br, Wh, Uh, Bh, img, bias);
    gru_main<<<256, 512, 0, stream>>>(x, h, img, bias, (float*)d_out, Brows);
}